// Round 12
// baseline (94.012 us; speedup 1.0000x reference)
//
#include <hip/hip_runtime.h>
#include <hip/hip_bf16.h>

// E_s = 0.5 * sum W[a,b,n] A[i,j,n] v[i,a,s] v[j,b,s]
// G[(j,n),(a,s)] = sum_b W[a,b,n] v[j,b,s]   (16384 x 192 bf16, 6 MB)
// t[i,(a,s)]     = sum_k A[i,k] G[k,(a,s)]   GEMM, K = A's contiguous order
// E_s            = 0.5 * sum_{i,a} v[i,a,s] t[i,(a,s)]
//
// R12 = R9 + ONE change: per-step raw s_barrier rally.
// Wave-private LDS staging -> no __syncthreads (no vmcnt/lgkmcnt(0) drains);
// A-prefetch stays in flight across steps. The rally (no memory semantics
// needed: LDS is wave-private, B read-only) keeps the block's 8 waves on the
// same step so their IDENTICAL per-step B-frags stay L1-resident (24 KB
// window < 32 KB L1) -> B L2 traffic /8 (R9 without rally thrashed L1:
// ~1.6 GB from L2 ~= its 45 us regression).

typedef __attribute__((ext_vector_type(8))) short short8;   // bf16x8 MFMA frag
typedef __attribute__((ext_vector_type(4))) float floatx4;

#define GF_U4 393216   // 12 fragcols * 2048 kb * 16 ci (uint4) = 6 MB
#define NBLK  512

__device__ __forceinline__ unsigned pk2(float lo, float hi) {
    __hip_bfloat162 h = __float22bfloat162_rn(make_float2(lo, hi));
    union { __hip_bfloat162 h; unsigned u; } c; c.h = h; return c.u;
}

// Gf layout: [f=c/16][kb=k/8][ci=c%16] uint4 (8 bf16 k for column c);
// c = a*64+s, k = j*4+n (A's contiguous order). Validated R4/R6/R9.
__global__ void prep_G(const float* __restrict__ W, const float* __restrict__ v,
                       uint4* __restrict__ Gf) {
    __shared__ float Wl[36];
    if (threadIdx.x < 36) Wl[threadIdx.x] = W[threadIdx.x];
    __syncthreads();
    int g = blockIdx.x * 256 + threadIdx.x;   // 1536*256 == GF_U4
    int ci = g & 15;
    int kb = (g >> 4) & 2047;
    int f  = g >> 15;
    int c = f * 16 + ci;
    int a = c >> 6, s = c & 63;
    int j0 = kb * 2;
    float vv[2][3];
    #pragma unroll
    for (int jj = 0; jj < 2; ++jj)
        #pragma unroll
        for (int b = 0; b < 3; ++b)
            vv[jj][b] = v[((j0 + jj) * 3 + b) * 64 + s];
    float Gv[8];
    #pragma unroll
    for (int e = 0; e < 8; ++e) {
        int n = e & 3, jj = e >> 2;
        Gv[e] = Wl[(a*3+0)*4+n] * vv[jj][0] + Wl[(a*3+1)*4+n] * vv[jj][1]
              + Wl[(a*3+2)*4+n] * vv[jj][2];
    }
    Gf[g] = make_uint4(pk2(Gv[0],Gv[1]), pk2(Gv[2],Gv[3]),
                       pk2(Gv[4],Gv[5]), pk2(Gv[6],Gv[7]));
}

// 512 blocks = 32 i-tiles (128 rows) x 16 k-slices (1024 k). 8 waves/block:
// wave w owns rows [i0 + w*16, +16), all 192 cols, 32 steps of k=32.
// Per wave per step: 2 dwordx4 A-loads, 4 cvt_pk, 1 ds_write_b128,
// 1 ds_read_b128, 12 B dwordx4 (L1-shared across waves via rally), 12 MFMA.
__global__ __launch_bounds__(512, 2) void energy_main(
        const float* __restrict__ A, const float* __restrict__ v,
        const uint4* __restrict__ Gf, float* __restrict__ partials) {
    __shared__ __align__(16) char Lds[8 * 2048];   // per-wave 2 x 1 KB buffers
    __shared__ float El[8][192];

    const int tid = threadIdx.x;
    const int bid = blockIdx.x;
    const int slice = bid & 15;
    const int i0 = (bid >> 4) * 128;
    const int w = tid >> 6, lane = tid & 63;
    const int r  = lane >> 2, kp = lane & 3;     // staging: row, k-quad-pair
    const int rr = lane & 15, g4 = lane >> 4;    // fragment coords
    const int rowbase = i0 + w * 16;

    // ---- A staging source: float4 idx = row*4096 + slice*256 + t*8 + kp*2
    const floatx4* A4 = reinterpret_cast<const floatx4*>(A);
    const floatx4* aP = A4 + ((long)(rowbase + r) * 4096 + slice * 256 + kp * 2);

    // ---- wave-private LDS: row r (64 B of bf16 = 32 k), 16B granules
    // swizzled g' = g ^ (r&3); write granule kp, read granule g4.
    char* wQ = Lds + w * 2048 + r * 64 + ((kp ^ (r & 3)) << 4);
    const char* rQ = Lds + w * 2048 + rr * 64 + ((g4 ^ (rr & 3)) << 4);

    // ---- B pointer: uint4 idx = cf*32768 + (slice*128 + t*4 + g4)*16 + rr
    const uint4* bP = Gf + ((slice * 128 + g4) * 16 + rr);

    floatx4 acc[12];
    #pragma unroll
    for (int cf = 0; cf < 12; ++cf)
        #pragma unroll
        for (int rg = 0; rg < 4; ++rg) acc[cf][rg] = 0.0f;

    // ---- prologue: stage step 0 into buf0; prefetch step 1 into regs
    {
        floatx4 c0 = aP[0], c1 = aP[1];
        union { uint4 u; short8 s; } cv;
        cv.u = make_uint4(pk2(c0.x, c0.y), pk2(c0.z, c0.w),
                          pk2(c1.x, c1.y), pk2(c1.z, c1.w));
        *reinterpret_cast<uint4*>(wQ) = cv.u;
    }
    aP += 8;
    floatx4 p0 = aP[0], p1 = aP[1];
    aP += 8;

    for (int t = 0; t < 32; ++t) {
        // A fragment of step t (write(t) ordered before by in-wave lgkmcnt)
        short8 af = *reinterpret_cast<const short8*>(rQ + (t & 1) * 1024);
        // B fragments of step t (identical addrs across the block's 8 waves;
        // rally keeps them L1-resident)
        uint4 bu[12];
        #pragma unroll
        for (int cf = 0; cf < 12; ++cf)
            bu[cf] = bP[cf * 32768 + t * 64];
        // stage step t+1 (regs -> other buffer); counted lgkmcnt only
        if (t < 31) {
            union { uint4 u; short8 s; } cv;
            cv.u = make_uint4(pk2(p0.x, p0.y), pk2(p0.z, p0.w),
                              pk2(p1.x, p1.y), pk2(p1.z, p1.w));
            *reinterpret_cast<uint4*>(wQ + ((t + 1) & 1) * 1024) = cv.u;
        }
        // issue loads for step t+2 (stay in flight across the whole step:
        // no drain anywhere in this loop)
        if (t < 30) {
            p0 = aP[0];
            p1 = aP[1];
            aP += 8;
        }
        #pragma unroll
        for (int cf = 0; cf < 12; ++cf) {
            union { uint4 u; short8 s; } bc; bc.u = bu[cf];
            acc[cf] = __builtin_amdgcn_mfma_f32_16x16x32_bf16(
                af, bc.s, acc[cf], 0, 0, 0);
        }
        // RALLY: raw s_barrier (no waitcnt drain) — keeps waves step-aligned
        __builtin_amdgcn_s_barrier();
    }

    // ---- epilogue: E_s += t[i,c] * v[i,a,s]; C: col = lane&15, row = g4*4+rg
    float cont[12];
    #pragma unroll
    for (int cf = 0; cf < 12; ++cf) {
        int c = cf * 16 + rr;
        int a = c >> 6, s = c & 63;
        float sum = 0.0f;
        #pragma unroll
        for (int rg = 0; rg < 4; ++rg) {
            int i = rowbase + g4 * 4 + rg;
            sum += acc[cf][rg] * v[(i * 3 + a) * 64 + s];
        }
        sum += __shfl_xor(sum, 16);
        sum += __shfl_xor(sum, 32);
        cont[cf] = sum;
    }
    if (lane < 16) {
        #pragma unroll
        for (int cf = 0; cf < 12; ++cf)
            El[w][cf * 16 + lane] = cont[cf];
    }
    __syncthreads();   // the only full barrier
    if (tid < 64) {
        float t = 0.0f;
        #pragma unroll
        for (int w2 = 0; w2 < 8; ++w2)
            #pragma unroll
            for (int a = 0; a < 3; ++a)
                t += El[w2][a * 64 + tid];
        partials[bid * 64 + tid] = 0.5f * t;
    }
}

// 512 threads: chunk = tid>>6, s = tid&63; fixed order -> deterministic
__global__ void reduce_out(const float* __restrict__ partials, float* __restrict__ out) {
    __shared__ float red[8][64];
    int tid = threadIdx.x;
    int chunk = tid >> 6, s = tid & 63;
    float a = 0.0f;
    for (int m = 0; m < NBLK / 8; ++m)
        a += partials[((m << 3) + chunk) * 64 + s];
    red[chunk][s] = a;
    __syncthreads();
    if (tid < 64) {
        float t = 0.0f;
        #pragma unroll
        for (int c = 0; c < 8; ++c) t += red[c][tid];
        out[tid] = t;
    }
}

extern "C" void kernel_launch(void* const* d_in, const int* in_sizes, int n_in,
                              void* d_out, int out_size, void* d_ws, size_t ws_size,
                              hipStream_t stream) {
    const float* W = (const float*)d_in[0];   // [3][3][4]
    const float* A = (const float*)d_in[1];   // [4096][4096][4]
    const float* v = (const float*)d_in[2];   // [4096][3][64]
    float* out = (float*)d_out;               // [64] f32
    uint4* Gf = (uint4*)d_ws;                                      // 6 MB
    float* partials = (float*)((char*)d_ws + (size_t)GF_U4 * 16);  // +128 KB

    hipLaunchKernelGGL(prep_G, dim3(GF_U4 / 256), dim3(256), 0, stream, W, v, Gf);
    hipLaunchKernelGGL(energy_main, dim3(NBLK), dim3(512), 0, stream, A, v, Gf, partials);
    hipLaunchKernelGGL(reduce_out, dim3(1), dim3(512), 0, stream, partials, out);
}

// Round 13
// 64.908 us; speedup vs baseline: 1.4484x; 1.4484x over previous
//
#include <hip/hip_runtime.h>
#include <hip/hip_bf16.h>

// E_s = 0.5 * sum_{a,b,n,i,j} W[a,b,n] A[i,j,n] v[i,a,s] v[j,b,s]
// Core: t[i,n,c] = sum_j A_n[i,j] * v[j,c], c=(b,s) in [0,192); epilogue is
// linear in t -> per-block/per-wave j-partials just add.
// R13 = R10 (measured best, 68.1 us: two-barrier double-buffer, contiguous
// cooperative staging, 2-deep reg prefetch, (512,2)) + ONE change: raw
// s_barrier + lgkmcnt(0)-only waits instead of __syncthreads. vmcnt is never
// drained -> A-prefetch (2-step window) and B-prefetch stay in flight across
// barriers; kills the ~900cy/step HBM restart bubble (28% of step time).

typedef __attribute__((ext_vector_type(8))) short short8;   // bf16x8 frag
typedef __attribute__((ext_vector_type(4))) float floatx4;  // f32x4 acc

#define VF_U4 (12*512*16)   // uint4 elements in v fragment buffer (1.5 MB)
#define NBLK  512

__device__ __forceinline__ unsigned short f2bf(float f) {
    union { float f; unsigned u; } x; x.f = f;
    unsigned r = x.u + 0x7fffu + ((x.u >> 16) & 1u);   // RTNE
    return (unsigned short)(r >> 16);
}
__device__ __forceinline__ unsigned pack2(float lo, float hi) {
    return (unsigned)f2bf(lo) | ((unsigned)f2bf(hi) << 16);
}

// Build bf16 B-operand fragments from v[4096][3][64]:
// vf layout: [f=c/16][kb=j/8][ci=c%16][je=j%8] bf16, i.e. uint4 index
// (f*512+kb)*16+ci holds 8 consecutive j for column c. A wave's B-frag load
// (16 cols x 32 k) is then 64 consecutive uint4 -> one coalesced dwordx4/lane.
__global__ void prep_vfrag(const float* __restrict__ v, uint4* __restrict__ vf) {
    int tid = blockIdx.x * 256 + threadIdx.x;
    if (tid >= VF_U4) return;
    int ci = tid & 15;
    int kb = (tid >> 4) & 511;
    int f  = tid >> 13;
    int c = f * 16 + ci;
    int b = c >> 6, s = c & 63;
    int j0 = kb * 8;
    unsigned q0 = pack2(v[((j0+0)*3+b)*64+s], v[((j0+1)*3+b)*64+s]);
    unsigned q1 = pack2(v[((j0+2)*3+b)*64+s], v[((j0+3)*3+b)*64+s]);
    unsigned q2 = pack2(v[((j0+4)*3+b)*64+s], v[((j0+5)*3+b)*64+s]);
    unsigned q3 = pack2(v[((j0+6)*3+b)*64+s], v[((j0+7)*3+b)*64+s]);
    vf[tid] = make_uint4(q0, q1, q2, q3);
}

// Main: 512 blocks = 256 i-tiles (16 rows) x 2 j-halves (2048 each).
// 512 threads = 8 waves: wave w -> kh=w>>2 (k-half of BK=64), ws=w&3 (48-col slice).
// Per wave per BK-step: 4 A-frags (LDS, swizzled), 3 B-frags (global), 12 MFMA.
__global__ __launch_bounds__(512, 2) void energy_main(
        const float* __restrict__ A, const float* __restrict__ v,
        const float* __restrict__ W, const uint4* __restrict__ vf,
        float* __restrict__ partials) {
    // A tiles: 2 bufs x 4 n x 16 rows x 128 B (64 bf16 j), XOR-swizzled granules
    __shared__ __align__(16) unsigned As32[4096];   // 16 KB
    __shared__ float Wl[36];
    __shared__ float El[64];

    const int tid = threadIdx.x;
    const int bid = blockIdx.x;
    const int ib = bid >> 1, jh = bid & 1;
    const int i0 = ib * 16;
    const int jbase = jh * 2048;

    if (tid < 36) Wl[tid] = W[tid];
    if (tid < 64) El[tid] = 0.0f;

    const int lane = tid & 63;
    const int w = tid >> 6;
    const int kh = w >> 2;
    const int ws = w & 3;

    // ---- staging indices (all 512 threads): r=0..15 row, jp=0..31 j-pair
    const int r  = tid >> 5;
    const int jp = tid & 31;
    const long arowBase = (long)(i0 + r) * 4096 + jbase + 2 * jp;  // float4 units
    const int aWrIdx = r * 32 + (((jp >> 2) ^ (r & 7)) << 2) + (jp & 3); // u32 units

    // ---- A-frag read offset: row rr, granule (kh*4 + lane>>4) ^ (rr&7)
    const int rr = lane & 15;
    const int gA = (kh * 4 + (lane >> 4)) ^ (rr & 7);
    const int aRdOff = rr * 128 + gA * 16;   // bytes; + n*2048 + buf*8192

    // ---- B-frag base (uint4 index step = 8 kb per 64 j)
    const int kbBase = (jbase + kh * 32) >> 3;

    floatx4 acc[4][3];
    #pragma unroll
    for (int n = 0; n < 4; ++n)
        #pragma unroll
        for (int cf = 0; cf < 3; ++cf)
            #pragma unroll
            for (int q = 0; q < 4; ++q) acc[n][cf][q] = 0.0f;

    const floatx4* A4 = reinterpret_cast<const floatx4*>(A);

    // prologue: stage tile 0 into buf 0; load tiles 1,2 into reg sets; B(0)
    {
        floatx4 a0 = A4[arowBase];
        floatx4 a1 = A4[arowBase + 1];
        As32[0*512 + aWrIdx] = pack2(a0.x, a1.x);
        As32[1*512 + aWrIdx] = pack2(a0.y, a1.y);
        As32[2*512 + aWrIdx] = pack2(a0.z, a1.z);
        As32[3*512 + aWrIdx] = pack2(a0.w, a1.w);
    }
    floatx4 rA0[2], rA1[2];
    #pragma unroll
    for (int ph = 0; ph < 2; ++ph) {            // tiles 1 and 2
        long o = arowBase + (long)(1 + ph) * 64;
        rA0[ph] = A4[o];
        rA1[ph] = A4[o + 1];
    }
    short8 bc[3];
    #pragma unroll
    for (int cf = 0; cf < 3; ++cf)
        bc[cf] = *reinterpret_cast<const short8*>(vf + ((ws*3+cf)*512 + kbBase)*16 + lane);
    asm volatile("s_waitcnt lgkmcnt(0)" ::: "memory");   // tile-0 writes visible

    int cur = 0;
    for (int tt = 0; tt < 32; tt += 2) {
        #pragma unroll
        for (int ph = 0; ph < 2; ++ph) {        // static reg-set index (rule #20)
            const int t = tt + ph;
            __builtin_amdgcn_s_barrier();       // B1: buf[cur] published
            short8 bn[3];
            if (t < 31) {                       // B(t+1) prefetch (L2-resident)
                int kb = kbBase + (t + 1) * 8;
                #pragma unroll
                for (int cf = 0; cf < 3; ++cf)
                    bn[cf] = *reinterpret_cast<const short8*>(vf + ((ws*3+cf)*512 + kb)*16 + lane);
            }
            const char* ab = reinterpret_cast<const char*>(As32) + cur * 8192 + aRdOff;
            short8 af[4];
            #pragma unroll
            for (int n = 0; n < 4; ++n)
                af[n] = *reinterpret_cast<const short8*>(ab + n * 2048);
            #pragma unroll
            for (int n = 0; n < 4; ++n)
                #pragma unroll
                for (int cf = 0; cf < 3; ++cf)
                    acc[n][cf] = __builtin_amdgcn_mfma_f32_16x16x32_bf16(
                        af[n], bc[cf], acc[n][cf], 0, 0, 0);
            // reads retired (MFMA consumed them); ~free drain, NO vmcnt drain
            asm volatile("s_waitcnt lgkmcnt(0)" ::: "memory");
            __builtin_amdgcn_s_barrier();       // B2: safe to overwrite buf[cur^1]
            if (t < 31) {                       // write tile t+1 (reg set ph);
                const int base = (cur ^ 1) * 2048 + aWrIdx;   // counted vmcnt only
                As32[base + 0*512] = pack2(rA0[ph].x, rA1[ph].x);
                As32[base + 1*512] = pack2(rA0[ph].y, rA1[ph].y);
                As32[base + 2*512] = pack2(rA0[ph].z, rA1[ph].z);
                As32[base + 3*512] = pack2(rA0[ph].w, rA1[ph].w);
            }
            asm volatile("s_waitcnt lgkmcnt(0)" ::: "memory");  // writes visible
            if (t < 29) {                       // refill set ph with tile t+3
                long o = arowBase + (long)(t + 3) * 64;
                rA0[ph] = A4[o];
                rA1[ph] = A4[o + 1];
            }
            if (t < 31) { bc[0] = bn[0]; bc[1] = bn[1]; bc[2] = bn[2]; }
            cur ^= 1;
        }
    }

    // ---- epilogue: E_partial[s] += t[i,n,c] * P[i,n,c], P = sum_a W[a,b,n] v[i,a,s]
    // C layout: col = lane&15 (c within frag), row = (lane>>4)*4 + reg (i within tile)
    float cont[3];
    #pragma unroll
    for (int cf = 0; cf < 3; ++cf) {
        int c = ws * 48 + cf * 16 + rr;
        int b = c >> 6, s = c & 63;
        float sum = 0.0f;
        #pragma unroll
        for (int rg = 0; rg < 4; ++rg) {
            int i = i0 + (lane >> 4) * 4 + rg;
            float v0 = v[(i * 3 + 0) * 64 + s];
            float v1 = v[(i * 3 + 1) * 64 + s];
            float v2 = v[(i * 3 + 2) * 64 + s];
            #pragma unroll
            for (int n = 0; n < 4; ++n) {
                float P = Wl[b * 4 + n] * v0 + Wl[12 + b * 4 + n] * v1
                        + Wl[24 + b * 4 + n] * v2;
                sum += acc[n][cf][rg] * P;
            }
        }
        cont[cf] = sum;
    }
    #pragma unroll
    for (int cf = 0; cf < 3; ++cf) {           // sum the 4 i-groups (same c)
        cont[cf] += __shfl_xor(cont[cf], 16);
        cont[cf] += __shfl_xor(cont[cf], 32);
    }
    __syncthreads();
    if (lane < 16) {
        #pragma unroll
        for (int cf = 0; cf < 3; ++cf) {
            int s = (ws * 48 + cf * 16 + lane) & 63;
            atomicAdd(&El[s], cont[cf]);       // LDS atomics, block-local
        }
    }
    __syncthreads();
    if (tid < 64) partials[bid * 64 + tid] = 0.5f * El[tid];
}

// 512 threads: chunk = tid>>6 (8 chunks), s = tid&63; fixed order -> deterministic
__global__ void reduce_out(const float* __restrict__ partials, float* __restrict__ out) {
    __shared__ float red[8][64];
    int tid = threadIdx.x;
    int chunk = tid >> 6, s = tid & 63;
    float a = 0.0f;
    for (int m = 0; m < NBLK / 8; ++m)
        a += partials[((m << 3) + chunk) * 64 + s];
    red[chunk][s] = a;
    __syncthreads();
    if (tid < 64) {
        float t = 0.0f;
        #pragma unroll
        for (int c = 0; c < 8; ++c) t += red[c][tid];
        out[tid] = t;
    }
}

extern "C" void kernel_launch(void* const* d_in, const int* in_sizes, int n_in,
                              void* d_out, int out_size, void* d_ws, size_t ws_size,
                              hipStream_t stream) {
    const float* W = (const float*)d_in[0];   // [3][3][4]
    const float* A = (const float*)d_in[1];   // [4096][4096][4]
    const float* v = (const float*)d_in[2];   // [4096][3][64]
    float* out = (float*)d_out;               // [64] f32
    uint4* vf = (uint4*)d_ws;                                  // 1.5 MB
    float* partials = (float*)((char*)d_ws + (size_t)VF_U4 * 16); // +128 KB

    hipLaunchKernelGGL(prep_vfrag, dim3((VF_U4 + 255) / 256), dim3(256), 0, stream, v, vf);
    hipLaunchKernelGGL(energy_main, dim3(NBLK), dim3(512), 0, stream, A, v, W, vf, partials);
    hipLaunchKernelGGL(reduce_out, dim3(1), dim3(512), 0, stream, partials, out);
}

// Round 14
// 63.785 us; speedup vs baseline: 1.4739x; 1.0176x over previous
//
#include <hip/hip_runtime.h>
#include <hip/hip_bf16.h>

// E_s = 0.5 * sum_{a,b,n,i,j} W[a,b,n] A[i,j,n] v[i,a,s] v[j,b,s]
// Core: t[i,n,c] = sum_j A_n[i,j] * v[j,c], c=(b,s) in [0,192); epilogue is
// linear in t -> per-block/per-wave j-partials just add.
// R14 = R13 (raw s_barrier, no vmcnt drains, 2-deep reg prefetch) + ONE
// change: SINGLE barrier per K-step. Step t reads buf[cur], writes buf[cur^1]
// (no reader of cur^1 this step) -> only sync needed is lgkm(0)+barrier at
// step end. 33 barriers/block instead of 64; the one lgkm wait sits AFTER
// the refill-load issue so the HBM stream is never delayed by it.

typedef __attribute__((ext_vector_type(8))) short short8;   // bf16x8 frag
typedef __attribute__((ext_vector_type(4))) float floatx4;  // f32x4 acc

#define VF_U4 (12*512*16)   // uint4 elements in v fragment buffer (1.5 MB)
#define NBLK  512

__device__ __forceinline__ unsigned short f2bf(float f) {
    union { float f; unsigned u; } x; x.f = f;
    unsigned r = x.u + 0x7fffu + ((x.u >> 16) & 1u);   // RTNE
    return (unsigned short)(r >> 16);
}
__device__ __forceinline__ unsigned pack2(float lo, float hi) {
    return (unsigned)f2bf(lo) | ((unsigned)f2bf(hi) << 16);
}

// Build bf16 B-operand fragments from v[4096][3][64]:
// vf layout: [f=c/16][kb=j/8][ci=c%16][je=j%8] bf16, i.e. uint4 index
// (f*512+kb)*16+ci holds 8 consecutive j for column c. A wave's B-frag load
// (16 cols x 32 k) is then 64 consecutive uint4 -> one coalesced dwordx4/lane.
__global__ void prep_vfrag(const float* __restrict__ v, uint4* __restrict__ vf) {
    int tid = blockIdx.x * 256 + threadIdx.x;
    if (tid >= VF_U4) return;
    int ci = tid & 15;
    int kb = (tid >> 4) & 511;
    int f  = tid >> 13;
    int c = f * 16 + ci;
    int b = c >> 6, s = c & 63;
    int j0 = kb * 8;
    unsigned q0 = pack2(v[((j0+0)*3+b)*64+s], v[((j0+1)*3+b)*64+s]);
    unsigned q1 = pack2(v[((j0+2)*3+b)*64+s], v[((j0+3)*3+b)*64+s]);
    unsigned q2 = pack2(v[((j0+4)*3+b)*64+s], v[((j0+5)*3+b)*64+s]);
    unsigned q3 = pack2(v[((j0+6)*3+b)*64+s], v[((j0+7)*3+b)*64+s]);
    vf[tid] = make_uint4(q0, q1, q2, q3);
}

// Main: 512 blocks = 256 i-tiles (16 rows) x 2 j-halves (2048 each).
// 512 threads = 8 waves: wave w -> kh=w>>2 (k-half of BK=64), ws=w&3 (48-col slice).
// Per wave per BK-step: 4 A-frags (LDS, swizzled), 3 B-frags (global), 12 MFMA.
__global__ __launch_bounds__(512, 2) void energy_main(
        const float* __restrict__ A, const float* __restrict__ v,
        const float* __restrict__ W, const uint4* __restrict__ vf,
        float* __restrict__ partials) {
    // A tiles: 2 bufs x 4 n x 16 rows x 128 B (64 bf16 j), XOR-swizzled granules
    __shared__ __align__(16) unsigned As32[4096];   // 16 KB
    __shared__ float Wl[36];
    __shared__ float El[64];

    const int tid = threadIdx.x;
    const int bid = blockIdx.x;
    const int ib = bid >> 1, jh = bid & 1;
    const int i0 = ib * 16;
    const int jbase = jh * 2048;

    if (tid < 36) Wl[tid] = W[tid];
    if (tid < 64) El[tid] = 0.0f;

    const int lane = tid & 63;
    const int w = tid >> 6;
    const int kh = w >> 2;
    const int ws = w & 3;

    // ---- staging indices (all 512 threads): r=0..15 row, jp=0..31 j-pair
    const int r  = tid >> 5;
    const int jp = tid & 31;
    const long arowBase = (long)(i0 + r) * 4096 + jbase + 2 * jp;  // float4 units
    const int aWrIdx = r * 32 + (((jp >> 2) ^ (r & 7)) << 2) + (jp & 3); // u32 units

    // ---- A-frag read offset: row rr, granule (kh*4 + lane>>4) ^ (rr&7)
    const int rr = lane & 15;
    const int gA = (kh * 4 + (lane >> 4)) ^ (rr & 7);
    const int aRdOff = rr * 128 + gA * 16;   // bytes; + n*2048 + buf*8192

    // ---- B-frag base (uint4 index step = 8 kb per 64 j)
    const int kbBase = (jbase + kh * 32) >> 3;

    floatx4 acc[4][3];
    #pragma unroll
    for (int n = 0; n < 4; ++n)
        #pragma unroll
        for (int cf = 0; cf < 3; ++cf)
            #pragma unroll
            for (int q = 0; q < 4; ++q) acc[n][cf][q] = 0.0f;

    const floatx4* A4 = reinterpret_cast<const floatx4*>(A);

    // prologue: stage tile 0 into buf 0; load tiles 1,2 into reg sets; B(0)
    {
        floatx4 a0 = A4[arowBase];
        floatx4 a1 = A4[arowBase + 1];
        As32[0*512 + aWrIdx] = pack2(a0.x, a1.x);
        As32[1*512 + aWrIdx] = pack2(a0.y, a1.y);
        As32[2*512 + aWrIdx] = pack2(a0.z, a1.z);
        As32[3*512 + aWrIdx] = pack2(a0.w, a1.w);
    }
    floatx4 rA0[2], rA1[2];
    #pragma unroll
    for (int ph = 0; ph < 2; ++ph) {            // tiles 1 and 2
        long o = arowBase + (long)(1 + ph) * 64;
        rA0[ph] = A4[o];
        rA1[ph] = A4[o + 1];
    }
    short8 bc[3];
    #pragma unroll
    for (int cf = 0; cf < 3; ++cf)
        bc[cf] = *reinterpret_cast<const short8*>(vf + ((ws*3+cf)*512 + kbBase)*16 + lane);
    asm volatile("s_waitcnt lgkmcnt(0)" ::: "memory");   // tile-0 writes visible
    __builtin_amdgcn_s_barrier();

    int cur = 0;
    for (int tt = 0; tt < 32; tt += 2) {
        #pragma unroll
        for (int ph = 0; ph < 2; ++ph) {        // static reg-set index (rule #20)
            const int t = tt + ph;
            // B(t+1) prefetch (L2-resident vf)
            short8 bn[3];
            if (t < 31) {
                int kb = kbBase + (t + 1) * 8;
                #pragma unroll
                for (int cf = 0; cf < 3; ++cf)
                    bn[cf] = *reinterpret_cast<const short8*>(vf + ((ws*3+cf)*512 + kb)*16 + lane);
            }
            // A frags of tile t from buf[cur]
            const char* ab = reinterpret_cast<const char*>(As32) + cur * 8192 + aRdOff;
            short8 af[4];
            #pragma unroll
            for (int n = 0; n < 4; ++n)
                af[n] = *reinterpret_cast<const short8*>(ab + n * 2048);
            // write tile t+1 (reg set ph) into buf[cur^1] — no reader this step
            if (t < 31) {
                const int base = (cur ^ 1) * 2048 + aWrIdx;
                As32[base + 0*512] = pack2(rA0[ph].x, rA1[ph].x);
                As32[base + 1*512] = pack2(rA0[ph].y, rA1[ph].y);
                As32[base + 2*512] = pack2(rA0[ph].z, rA1[ph].z);
                As32[base + 3*512] = pack2(rA0[ph].w, rA1[ph].w);
            }
            // refill reg set ph with tile t+3 (issue BEFORE any wave-local wait)
            if (t < 29) {
                long o = arowBase + (long)(t + 3) * 64;
                rA0[ph] = A4[o];
                rA1[ph] = A4[o + 1];
            }
            #pragma unroll
            for (int n = 0; n < 4; ++n)
                #pragma unroll
                for (int cf = 0; cf < 3; ++cf)
                    acc[n][cf] = __builtin_amdgcn_mfma_f32_16x16x32_bf16(
                        af[n], bc[cf], acc[n][cf], 0, 0, 0);
            if (t < 31) { bc[0] = bn[0]; bc[1] = bn[1]; bc[2] = bn[2]; }
            // publish tile t+1; reads of buf[cur] already retired (MFMA).
            // NO vmcnt drain: refill/B loads stay in flight across the barrier.
            asm volatile("s_waitcnt lgkmcnt(0)" ::: "memory");
            __builtin_amdgcn_s_barrier();
            cur ^= 1;
        }
    }

    // ---- epilogue: E_partial[s] += t[i,n,c] * P[i,n,c], P = sum_a W[a,b,n] v[i,a,s]
    // C layout: col = lane&15 (c within frag), row = (lane>>4)*4 + reg (i within tile)
    float cont[3];
    #pragma unroll
    for (int cf = 0; cf < 3; ++cf) {
        int c = ws * 48 + cf * 16 + rr;
        int b = c >> 6, s = c & 63;
        float sum = 0.0f;
        #pragma unroll
        for (int rg = 0; rg < 4; ++rg) {
            int i = i0 + (lane >> 4) * 4 + rg;
            float v0 = v[(i * 3 + 0) * 64 + s];
            float v1 = v[(i * 3 + 1) * 64 + s];
            float v2 = v[(i * 3 + 2) * 64 + s];
            #pragma unroll
            for (int n = 0; n < 4; ++n) {
                float P = Wl[b * 4 + n] * v0 + Wl[12 + b * 4 + n] * v1
                        + Wl[24 + b * 4 + n] * v2;
                sum += acc[n][cf][rg] * P;
            }
        }
        cont[cf] = sum;
    }
    #pragma unroll
    for (int cf = 0; cf < 3; ++cf) {           // sum the 4 i-groups (same c)
        cont[cf] += __shfl_xor(cont[cf], 16);
        cont[cf] += __shfl_xor(cont[cf], 32);
    }
    __syncthreads();
    if (lane < 16) {
        #pragma unroll
        for (int cf = 0; cf < 3; ++cf) {
            int s = (ws * 48 + cf * 16 + lane) & 63;
            atomicAdd(&El[s], cont[cf]);       // LDS atomics, block-local
        }
    }
    __syncthreads();
    if (tid < 64) partials[bid * 64 + tid] = 0.5f * El[tid];
}

// 512 threads: chunk = tid>>6 (8 chunks), s = tid&63; fixed order -> deterministic
__global__ void reduce_out(const float* __restrict__ partials, float* __restrict__ out) {
    __shared__ float red[8][64];
    int tid = threadIdx.x;
    int chunk = tid >> 6, s = tid & 63;
    float a = 0.0f;
    for (int m = 0; m < NBLK / 8; ++m)
        a += partials[((m << 3) + chunk) * 64 + s];
    red[chunk][s] = a;
    __syncthreads();
    if (tid < 64) {
        float t = 0.0f;
        #pragma unroll
        for (int c = 0; c < 8; ++c) t += red[c][tid];
        out[tid] = t;
    }
}

extern "C" void kernel_launch(void* const* d_in, const int* in_sizes, int n_in,
                              void* d_out, int out_size, void* d_ws, size_t ws_size,
                              hipStream_t stream) {
    const float* W = (const float*)d_in[0];   // [3][3][4]
    const float* A = (const float*)d_in[1];   // [4096][4096][4]
    const float* v = (const float*)d_in[2];   // [4096][3][64]
    float* out = (float*)d_out;               // [64] f32
    uint4* vf = (uint4*)d_ws;                                  // 1.5 MB
    float* partials = (float*)((char*)d_ws + (size_t)VF_U4 * 16); // +128 KB

    hipLaunchKernelGGL(prep_vfrag, dim3((VF_U4 + 255) / 256), dim3(256), 0, stream, v, vf);
    hipLaunchKernelGGL(energy_main, dim3(NBLK), dim3(512), 0, stream, A, v, W, vf, partials);
    hipLaunchKernelGGL(reduce_out, dim3(1), dim3(512), 0, stream, partials, out);
}